// Round 2
// baseline (20393.817 us; speedup 1.0000x reference)
//
#include <hip/hip_runtime.h>
#include <hip/hip_fp16.h>

#define HDIM 256
#define LSEQ 512
#define PRED 96
#define NTHR 512   // 8 waves; wave w owns rows [32w,32w+32) of each gate block

typedef _Float16 f16x8 __attribute__((ext_vector_type(8)));
typedef _Float16 f16x4 __attribute__((ext_vector_type(4)));
typedef float f32x4 __attribute__((ext_vector_type(4)));

__device__ __forceinline__ float sigm(float x) { return 1.f / (1.f + __expf(-x)); }
__device__ __forceinline__ float tanh_(float x) { float t = __expf(2.f * x); return 1.f - 2.f / (t + 1.f); }

// One batch column per block (256 blocks -> full chip, no downclock regime).
// h state double-buffered, split f16 hi/lo (hi+lo == f32 h to ~2^-22).
// All lanes read the SAME h k-slice per (q,kt) -> LDS broadcast, conflict-free.
struct __align__(16) RecSmem {
  _Float16 h[2][2][256];  // [buf][hi/lo][k]  : 2 KiB
  float xv[LSEQ];
  float red[8];
  float inp;
};

// park a f16x8 in AGPRs (tied-operand class cast; copy happens once, pre-loop)
#define CAST_A(DST, SRC) asm("" : "=a"(DST) : "0"(SRC))

#define ROFF(G, S) (256 * (G) + 32 * w + 16 * (S) + 4 * q)

#define DECL_MM                                                                \
  f16x8 A[6][8];   /* this wave's 6 A-tiles x 8 k-frags -> 192 AGPRs */        \
  f32x4 biasC[6];  /* folded into MFMA C operand of kt=0 */                    \
  f16x8 bh[8], bl[8];                                                          \
  f32x4 ac[6];                                                                 \
  float hold[2][4]; /* h_old for this lane's 8 rows, f32, register-resident */

// A-frag (m89/m91 layout, proven in round-1 pass): lane(n,q) holds
// row ROFF(g,s)+n, k = 32kt + 8q + i.  fp32 -> f16 RN.
#define LOADA_ALL(WPTR)                                                        \
  _Pragma("unroll") for (int g = 0; g < 3; ++g)                                \
  _Pragma("unroll") for (int s = 0; s < 2; ++s)                                \
  _Pragma("unroll") for (int kt = 0; kt < 8; ++kt) {                           \
    const float* ap = (WPTR) + (size_t)(256 * g + 32 * w + 16 * s + n) * HDIM  \
                      + 32 * kt + 8 * q;                                       \
    const float4 a0 = *(const float4*)ap;                                      \
    const float4 a1 = *(const float4*)(ap + 4);                                \
    f16x8 tf;                                                                  \
    tf[0] = (_Float16)a0.x; tf[1] = (_Float16)a0.y;                            \
    tf[2] = (_Float16)a0.z; tf[3] = (_Float16)a0.w;                            \
    tf[4] = (_Float16)a1.x; tf[5] = (_Float16)a1.y;                            \
    tf[6] = (_Float16)a1.z; tf[7] = (_Float16)a1.w;                            \
    CAST_A(A[g * 2 + s][kt], tf);                                              \
  }

// D[768,1] = Whh * (h_hi + h_lo), bias seeded via MFMA C operand.
// B-frag identical across lanes' n -> every output column equals the true
// matvec -> every lane holds valid rows m = 4q+r.  96 MFMA/wave/step.
#define MATCORE(PB)                                                            \
  _Pragma("unroll") for (int kt = 0; kt < 8; ++kt) {                           \
    bh[kt] = *(const f16x8*)&sm.h[PB][0][kt * 32 + 8 * q];                     \
    bl[kt] = *(const f16x8*)&sm.h[PB][1][kt * 32 + 8 * q];                     \
  }                                                                            \
  _Pragma("unroll") for (int m = 0; m < 6; ++m)                                \
    asm("v_mfma_f32_16x16x32_f16 %0, %1, %2, %3"                               \
        : "=&v"(ac[m]) : "a"(A[m][0]), "v"(bh[0]), "v"(biasC[m]));             \
  _Pragma("unroll") for (int kt = 1; kt < 8; ++kt)                             \
  _Pragma("unroll") for (int m = 0; m < 6; ++m)                                \
    asm("v_mfma_f32_16x16x32_f16 %0, %1, %2, %0"                               \
        : "+v"(ac[m]) : "a"(A[m][kt]), "v"(bh[kt]));                           \
  _Pragma("unroll") for (int kt = 0; kt < 8; ++kt)                             \
  _Pragma("unroll") for (int m = 0; m < 6; ++m)                                \
    asm("v_mfma_f32_16x16x32_f16 %0, %1, %2, %0"                               \
        : "+v"(ac[m]) : "a"(A[m][kt]), "v"(bl[kt]));                           \
  asm volatile("s_nop 7\n\ts_nop 7"                                            \
               : "+v"(ac[0]), "+v"(ac[1]), "+v"(ac[2]),                        \
                 "+v"(ac[3]), "+v"(ac[4]), "+v"(ac[5]));

// Gate math (valid on ALL lanes); only n==0 lanes store h (and EXTRA).
#define GATES_STORE(PB, GIR, GIZ, GIN, ...)                                    \
  _Pragma("unroll") for (int s = 0; s < 2; ++s) {                              \
    f16x4 vh, vl;                                                              \
    _Pragma("unroll") for (int r = 0; r < 4; ++r) {                            \
      const int m0 = s, m1 = 2 + s, m2 = 4 + s;                                \
      const float rr = sigm((GIR) + ac[m0][r]);                                \
      const float zz = sigm((GIZ) + ac[m1][r]);                                \
      const float nn = tanh_(fmaf(rr, ac[m2][r], (GIN)));                      \
      const float hv = fmaf(zz, hold[s][r] - nn, nn);                          \
      hold[s][r] = hv;                                                         \
      const _Float16 hhi = (_Float16)hv;                                       \
      vh[r] = hhi;                                                             \
      vl[r] = (_Float16)(hv - (float)hhi);                                     \
    }                                                                          \
    if (n == 0) {                                                              \
      const int js = 32 * w + 16 * s + 4 * q;                                  \
      *(f16x4*)&sm.h[(PB) ^ 1][0][js] = vh;                                    \
      *(f16x4*)&sm.h[(PB) ^ 1][1][js] = vl;                                    \
      __VA_ARGS__                                                              \
    }                                                                          \
  }

// lgkmcnt-only barrier: LDS h handoff ordered; global stores/prefetches stay
// in flight across steps (no vmcnt(0) drain).
#define BAR asm volatile("s_waitcnt lgkmcnt(0)\n\ts_barrier" ::: "memory")

// =================== Kernel 1: encoder GRU layer 0 ===========================
__global__ __launch_bounds__(NTHR) void gru_l0(
    const float* __restrict__ x, const float* __restrict__ Wih0,
    const float* __restrict__ Whh0, const float* __restrict__ bih0,
    const float* __restrict__ bhh0, __half* __restrict__ ys) {
  __shared__ RecSmem sm;
  const int tid = threadIdx.x;
  const int w = tid >> 6, lane = tid & 63, n = lane & 15, q = lane >> 4;
  const int b = blockIdx.x;
  DECL_MM

  if (tid < LSEQ) sm.xv[tid] = x[(size_t)b * LSEQ + tid];
  {
    float* hz = (float*)&sm.h[0][0][0];
    if (tid < 512) hz[tid % 512] = 0.f;  // 2*2*256 halves = 512 floats
  }
  LOADA_ALL(Whh0);
  f32x4 wih_v[6], bihn_v[2];
#pragma unroll
  for (int g = 0; g < 3; ++g)
#pragma unroll
    for (int s = 0; s < 2; ++s) {
      const int off = ROFF(g, s);
      wih_v[g * 2 + s] = *(const f32x4*)(Wih0 + off);
      const f32x4 b4 = *(const f32x4*)(bhh0 + off);
      if (g < 2) biasC[g * 2 + s] = b4 + *(const f32x4*)(bih0 + off);
      else { biasC[g * 2 + s] = b4; bihn_v[s] = *(const f32x4*)(bih0 + off); }
    }
#pragma unroll
  for (int s = 0; s < 2; ++s)
#pragma unroll
    for (int r = 0; r < 4; ++r) hold[s][r] = 0.f;
  __syncthreads();

  int pb = 0;
#pragma unroll 1
  for (int t = 0; t < LSEQ; ++t) {
    MATCORE(pb);
    const float xt = sm.xv[t];
    GATES_STORE(pb, xt * wih_v[m0][r], xt * wih_v[m1][r],
                fmaf(xt, wih_v[m2][r], bihn_v[s][r]),
                *(f16x4*)(ys + ((size_t)b * LSEQ + t) * HDIM + js) = vh;);
    pb ^= 1;
    BAR;
  }
}

// ============ Kernel 2: GI1 = ys0 @ W_ih1^T + b_ih1 (unchanged, proven) ======
__global__ __launch_bounds__(256) void gemm_gi(
    const float* __restrict__ Wih1, const float* __restrict__ bih1,
    const __half* __restrict__ ys, __half* __restrict__ gi) {
  const int lane = threadIdx.x & 63;
  const int wv = threadIdx.x >> 6;
  const size_t bt0 = (size_t)blockIdx.x << 4;
  const int n = lane & 15, q = lane >> 4;

  f16x8 bfr[8];
  const __half* yrow = ys + (bt0 + n) * HDIM + q * 8;
#pragma unroll
  for (int kk = 0; kk < 8; ++kk) bfr[kk] = *(const f16x8*)(yrow + kk * 32);

#pragma unroll 1
  for (int mt = 0; mt < 12; ++mt) {
    const int j0 = (wv * 12 + mt) << 4;
    const float* arow = Wih1 + (size_t)(j0 + n) * HDIM + q * 8;
    f32x4 acc = {0.f, 0.f, 0.f, 0.f};
#pragma unroll
    for (int kk = 0; kk < 8; ++kk) {
      const float4 a0 = *(const float4*)(arow + kk * 32);
      const float4 a1 = *(const float4*)(arow + kk * 32 + 4);
      f16x8 af;
      af[0] = (_Float16)a0.x; af[1] = (_Float16)a0.y;
      af[2] = (_Float16)a0.z; af[3] = (_Float16)a0.w;
      af[4] = (_Float16)a1.x; af[5] = (_Float16)a1.y;
      af[6] = (_Float16)a1.z; af[7] = (_Float16)a1.w;
      acc = __builtin_amdgcn_mfma_f32_16x16x32_f16(af, bfr[kk], acc, 0, 0, 0);
    }
    const int jr = j0 + (q << 2);
    __half o4[4];
#pragma unroll
    for (int r2 = 0; r2 < 4; ++r2) o4[r2] = __float2half(acc[r2] + bih1[jr + r2]);
    *(uint2*)(gi + (bt0 + n) * 768 + jr) = *(uint2*)o4;
  }
}

// ====== Kernel 3: encoder GRU layer 1 (uses gi) + autoregressive decoder =====
// All lanes load the same gi addresses (single L2 line) -> valid on all lanes.
#define LOADGI(PF, T)                                                          \
  {                                                                            \
    const __half* gp = gi + ((size_t)b * LSEQ + (T)) * 768 + 32 * w + 4 * q;   \
    PF[0] = *(const uint2*)(gp);                                               \
    PF[1] = *(const uint2*)(gp + 16);                                          \
    PF[2] = *(const uint2*)(gp + 256);                                         \
    PF[3] = *(const uint2*)(gp + 272);                                         \
    PF[4] = *(const uint2*)(gp + 512);                                         \
    PF[5] = *(const uint2*)(gp + 528);                                         \
  }

#define STEP3(PF)                                                              \
  {                                                                            \
    MATCORE(pb);                                                               \
    float gif[6][4];                                                           \
    _Pragma("unroll") for (int m = 0; m < 6; ++m) {                            \
      const __half2* hp = (const __half2*)&PF[m];                              \
      const float2 f01 = __half22float2(hp[0]);                                \
      const float2 f23 = __half22float2(hp[1]);                                \
      gif[m][0] = f01.x; gif[m][1] = f01.y;                                    \
      gif[m][2] = f23.x; gif[m][3] = f23.y;                                    \
    }                                                                          \
    GATES_STORE(pb, gif[m0][r], gif[m1][r], gif[m2][r], ;);                    \
    pb ^= 1;                                                                   \
    BAR;                                                                       \
  }

__global__ __launch_bounds__(NTHR) void gru_l1dec(
    const float* __restrict__ Whh1, const float* __restrict__ bhh1,
    const float* __restrict__ Wdih, const float* __restrict__ Wdhh,
    const float* __restrict__ bdih, const float* __restrict__ bdhh,
    const float* __restrict__ Wo, const float* __restrict__ bo,
    const __half* __restrict__ gi, float* __restrict__ outp) {
  __shared__ RecSmem sm;
  const int tid = threadIdx.x;
  const int w = tid >> 6, lane = tid & 63, n = lane & 15, q = lane >> 4;
  const int b = blockIdx.x;
  DECL_MM

  {
    float* hz = (float*)&sm.h[0][0][0];
    if (tid < 512) hz[tid % 512] = 0.f;
  }
  LOADA_ALL(Whh1);
#pragma unroll
  for (int g = 0; g < 3; ++g)
#pragma unroll
    for (int s = 0; s < 2; ++s)
      biasC[g * 2 + s] = *(const f32x4*)(bhh1 + ROFF(g, s));
#pragma unroll
  for (int s = 0; s < 2; ++s)
#pragma unroll
    for (int r = 0; r < 4; ++r) hold[s][r] = 0.f;
  __syncthreads();

  // ---- phase 3: layer-1 recurrence; gi prefetched one step ahead ----
  uint2 pfA[6], pfB[6];
  LOADGI(pfA, 0);
  int pb = 0;
#pragma unroll 1
  for (int t = 0; t < LSEQ; t += 2) {
    LOADGI(pfB, t + 1);
    STEP3(pfA);
    LOADGI(pfA, (t + 2 < LSEQ) ? (t + 2) : (LSEQ - 1));  // clamp: harmless reload
    STEP3(pfB);
  }

  // ---- phase 4: autoregressive decoder (96 steps) ----
  LOADA_ALL(Wdhh);
  f32x4 wdih_v[6], bdihn_v[2], wo_v[2];
#pragma unroll
  for (int g = 0; g < 3; ++g)
#pragma unroll
    for (int s = 0; s < 2; ++s) {
      const int off = ROFF(g, s);
      wdih_v[g * 2 + s] = *(const f32x4*)(Wdih + off);
      const f32x4 b4 = *(const f32x4*)(bdhh + off);
      if (g < 2) biasC[g * 2 + s] = b4 + *(const f32x4*)(bdih + off);
      else { biasC[g * 2 + s] = b4; bdihn_v[s] = *(const f32x4*)(bdih + off); }
    }
#pragma unroll
  for (int s = 0; s < 2; ++s)
    wo_v[s] = *(const f32x4*)(Wo + 32 * w + 16 * s + 4 * q);
  const float bov = bo[0];
  if (tid == 0) sm.inp = 0.f;
  BAR;

#pragma unroll 1
  for (int t = 0; t < PRED; ++t) {
    const float it = sm.inp;
    MATCORE(pb);
    float c = 0.f;
    GATES_STORE(pb, it * wdih_v[m0][r], it * wdih_v[m1][r],
                fmaf(it, wdih_v[m2][r], bdihn_v[s][r]),
                c += wo_v[s][0] * hold[s][0] + wo_v[s][1] * hold[s][1] +
                     wo_v[s][2] * hold[s][2] + wo_v[s][3] * hold[s][3];);
    // c valid only on n==0 lanes (0,16,32,48); xor-16/32 stays within them.
    c += __shfl_xor(c, 16);
    c += __shfl_xor(c, 32);
    if (lane == 0) sm.red[w] = c;
    pb ^= 1;
    BAR;
    if (tid == 0) {
      float ov = bov;
#pragma unroll
      for (int ww = 0; ww < 8; ++ww) ov += sm.red[ww];
      outp[(size_t)b * PRED + t] = ov;
      sm.inp = ov;
    }
    BAR;
  }
}

extern "C" void kernel_launch(void* const* d_in, const int* in_sizes, int n_in,
                              void* d_out, int out_size, void* d_ws, size_t ws_size,
                              hipStream_t stream) {
  const float* x    = (const float*)d_in[0];
  const float* Wih0 = (const float*)d_in[1];
  const float* Whh0 = (const float*)d_in[2];
  const float* bih0 = (const float*)d_in[3];
  const float* bhh0 = (const float*)d_in[4];
  const float* Wih1 = (const float*)d_in[5];
  const float* Whh1 = (const float*)d_in[6];
  const float* bih1 = (const float*)d_in[7];
  const float* bhh1 = (const float*)d_in[8];
  const float* Wdih = (const float*)d_in[9];
  const float* Wdhh = (const float*)d_in[10];
  const float* bdih = (const float*)d_in[11];
  const float* bdhh = (const float*)d_in[12];
  const float* Wo   = (const float*)d_in[13];
  const float* bo   = (const float*)d_in[14];

  // ws layout: ys0 (f16, 64 MiB) | GI1 (f16, 192 MiB)
  __half* ys = (__half*)d_ws;
  __half* gi = ys + (size_t)256 * 512 * 256;

  gru_l0<<<256, NTHR, 0, stream>>>(x, Wih0, Whh0, bih0, bhh0, ys);
  gemm_gi<<<(256 * 512) / 16, 256, 0, stream>>>(Wih1, bih1, ys, gi);
  gru_l1dec<<<256, NTHR, 0, stream>>>(Whh1, bhh1, Wdih, Wdhh, bdih, bdhh,
                                      Wo, bo, gi, (float*)d_out);
}

// Round 4
// 4974.791 us; speedup vs baseline: 4.0994x; 4.0994x over previous
//
#include <hip/hip_runtime.h>
#include <hip/hip_fp16.h>

#define HDIM 256
#define LSEQ 512
#define PRED 96
#define NTHR 256  // 4 waves; wave w owns h-rows [64w, 64w+64)

typedef _Float16 f16x8 __attribute__((ext_vector_type(8)));
typedef _Float16 f16x4 __attribute__((ext_vector_type(4)));
typedef float f32x4 __attribute__((ext_vector_type(4)));
typedef unsigned int u32;

__device__ __forceinline__ float sigm(float x) { return 1.f / (1.f + __expf(-x)); }
__device__ __forceinline__ float tanh_(float x) { float t = __expf(2.f * x); return 1.f - 2.f / (t + 1.f); }

// One batch column per block, 256 blocks (full chip). 4 waves / 1 wave/SIMD:
// unified RF budget 512 regs/wave = the only shape where W_hh-f16 (1536 regs
// per block) + state fits with zero spills (R2's 30 GB FETCH was spill traffic).
// 12 MFMA tiles/wave (tau = 4*gate + slot): tau 0-5 AGPR, 6-10 VGPR, 11 LDS.
struct __align__(16) Smem {
  _Float16 h[2][2][256];   // [buf][hi/lo][row]: h split f16 hi+lo == f32
  _Float16 A11[4][5120];   // per-wave LDS A-tile; [kt][row][40] (pad 32->40:
                           //   group=(5n+q)%8 -> 2-way alias = free)
  _Float16 gib[2][800];    // staged gi double buffer (768 used)
  float tw[3][256], tb[3][256], bnh[256], wo[256];
  float xv[LSEQ];
  float red[4];
  float inp;
};  // ~56 KB

#define CAST_A(DST, SRC) asm("" : "=a"(DST) : "0"(SRC))

#define DECL_MM                                                                \
  f16x8 Aa[6][8]; /* 192 AGPR */                                               \
  f16x8 Av[5][8]; /* 160 VGPR */                                               \
  f32x4 ac[12];   /* 48 AGPR accumulators */                                   \
  f32x4 zc;       /* zero C-operand, AGPR */                                   \
  { f32x4 z4 = {0.f, 0.f, 0.f, 0.f}; asm("" : "=a"(zc) : "0"(z4)); }

// A-frag load (m89/m91 layout, proven R1/R2): lane(n,q) holds rows mb+n,
// k = 32kt + 8q + i. fp32 -> f16 RN.
#define LOADA(WPTR)                                                            \
  _Pragma("unroll") for (int tt = 0; tt < 12; ++tt) {                          \
    _Pragma("unroll") for (int kt = 0; kt < 8; ++kt) {                         \
      const float* ap = (WPTR) +                                               \
          (size_t)(256 * (tt >> 2) + 64 * w + 16 * (tt & 3) + n) * HDIM +      \
          32 * kt + 8 * q;                                                     \
      const float4 a0 = *(const float4*)ap;                                    \
      const float4 a1 = *(const float4*)(ap + 4);                              \
      f16x8 tf;                                                                \
      tf[0] = (_Float16)a0.x; tf[1] = (_Float16)a0.y;                          \
      tf[2] = (_Float16)a0.z; tf[3] = (_Float16)a0.w;                          \
      tf[4] = (_Float16)a1.x; tf[5] = (_Float16)a1.y;                          \
      tf[6] = (_Float16)a1.z; tf[7] = (_Float16)a1.w;                          \
      if (tt < 6) { CAST_A(Aa[tt][kt], tf); }                                  \
      else if (tt < 11) { Av[tt - 6][kt] = tf; }                               \
      else { *(f16x8*)(a11p + kt * 1280) = tf; }                               \
    }                                                                          \
  }

// MFMA: D,C in AGPR; A from AGPR ("a") or VGPR ("v"); B always VGPR broadcast.
#define MM_A_S(I, AF, B) asm("v_mfma_f32_16x16x32_f16 %0, %1, %2, %3" : "=a"(ac[I]) : "a"(AF), "v"(B), "a"(zc));
#define MM_A(I, AF, B)   asm("v_mfma_f32_16x16x32_f16 %0, %1, %2, %0" : "+a"(ac[I]) : "a"(AF), "v"(B));
#define MM_V_S(I, AF, B) asm("v_mfma_f32_16x16x32_f16 %0, %1, %2, %3" : "=a"(ac[I]) : "v"(AF), "v"(B), "a"(zc));
#define MM_V(I, AF, B)   asm("v_mfma_f32_16x16x32_f16 %0, %1, %2, %0" : "+a"(ac[I]) : "v"(AF), "v"(B));

#define R12S(KT, B, AL)                                                        \
  MM_A_S(0, Aa[0][KT], B) MM_A_S(1, Aa[1][KT], B) MM_A_S(2, Aa[2][KT], B)      \
  MM_A_S(3, Aa[3][KT], B) MM_A_S(4, Aa[4][KT], B) MM_A_S(5, Aa[5][KT], B)      \
  MM_V_S(6, Av[0][KT], B) MM_V_S(7, Av[1][KT], B) MM_V_S(8, Av[2][KT], B)      \
  MM_V_S(9, Av[3][KT], B) MM_V_S(10, Av[4][KT], B) MM_V_S(11, AL, B)
#define R12(KT, B, AL)                                                         \
  MM_A(0, Aa[0][KT], B) MM_A(1, Aa[1][KT], B) MM_A(2, Aa[2][KT], B)            \
  MM_A(3, Aa[3][KT], B) MM_A(4, Aa[4][KT], B) MM_A(5, Aa[5][KT], B)            \
  MM_V(6, Av[0][KT], B) MM_V(7, Av[1][KT], B) MM_V(8, Av[2][KT], B)            \
  MM_V(9, Av[3][KT], B) MM_V(10, Av[4][KT], B) MM_V(11, AL, B)

// D[768,1] = Whh*(h_hi + h_lo). B k-slices broadcast from LDS (q-only addr ->
// 16-lane same-address = free). 1-deep ping-pong prefetch: 24 MFMA (~116cy)
// covers LDS latency. ac seeded kt0-hi with zero C (biases handled outside).
#define MAT_STEP(PB)                                                           \
  {                                                                            \
    const char* hp = hq + (PB) * 1024;                                         \
    f16x8 bhA = *(const f16x8*)(hp);                                           \
    f16x8 blA = *(const f16x8*)(hp + 512);                                     \
    f16x8 aA  = *(const f16x8*)(a11p);                                         \
    f16x8 bhB = *(const f16x8*)(hp + 64);                                      \
    f16x8 blB = *(const f16x8*)(hp + 512 + 64);                                \
    f16x8 aB  = *(const f16x8*)(a11p + 1280);                                  \
    R12S(0, bhA, aA) R12(0, blA, aA)                                           \
    bhA = *(const f16x8*)(hp + 128); blA = *(const f16x8*)(hp + 512 + 128);    \
    aA = *(const f16x8*)(a11p + 2560);                                         \
    R12(1, bhB, aB) R12(1, blB, aB)                                            \
    bhB = *(const f16x8*)(hp + 192); blB = *(const f16x8*)(hp + 512 + 192);    \
    aB = *(const f16x8*)(a11p + 3840);                                         \
    R12(2, bhA, aA) R12(2, blA, aA)                                            \
    bhA = *(const f16x8*)(hp + 256); blA = *(const f16x8*)(hp + 512 + 256);    \
    aA = *(const f16x8*)(a11p + 5120);                                         \
    R12(3, bhB, aB) R12(3, blB, aB)                                            \
    bhB = *(const f16x8*)(hp + 320); blB = *(const f16x8*)(hp + 512 + 320);    \
    aB = *(const f16x8*)(a11p + 6400);                                         \
    R12(4, bhA, aA) R12(4, blA, aA)                                            \
    bhA = *(const f16x8*)(hp + 384); blA = *(const f16x8*)(hp + 512 + 384);    \
    aA = *(const f16x8*)(a11p + 7680);                                         \
    R12(5, bhB, aB) R12(5, blB, aB)                                            \
    bhB = *(const f16x8*)(hp + 448); blB = *(const f16x8*)(hp + 512 + 448);    \
    aB = *(const f16x8*)(a11p + 8960);                                         \
    R12(6, bhA, aA) R12(6, blA, aA)                                            \
    R12(7, bhB, aB) R12(7, blB, aB)                                            \
  }

// MFMA -> VALU(accvgpr_read) hazard fence; ac operands also order gate reads.
#define ACFENCE                                                                \
  asm volatile("s_nop 7\n\ts_nop 7"                                            \
               : "+a"(ac[0]), "+a"(ac[1]), "+a"(ac[2]), "+a"(ac[3]),           \
                 "+a"(ac[4]), "+a"(ac[5]), "+a"(ac[6]), "+a"(ac[7]),           \
                 "+a"(ac[8]), "+a"(ac[9]), "+a"(ac[10]), "+a"(ac[11]));

// lgkm-only barrier: LDS handoff ordered; global stores stay in flight.
#define BAR asm volatile("s_waitcnt lgkmcnt(0)\n\ts_barrier" ::: "memory")

// =================== Kernel 1: encoder GRU layer 0 ===========================
__global__ __launch_bounds__(NTHR, 1) void gru_l0(
    const float* __restrict__ x, const float* __restrict__ Wih0,
    const float* __restrict__ Whh0, const float* __restrict__ bih0,
    const float* __restrict__ bhh0, __half* __restrict__ ys) {
  __shared__ Smem sm;
  const int tid = threadIdx.x;
  const int w = tid >> 6, lane = tid & 63, n = lane & 15, q = lane >> 4;
  const int b = blockIdx.x;
  DECL_MM
  char* a11p = (char*)sm.A11 + w * 10240 + n * 80 + q * 16;
  const char* hq = (const char*)sm.h + q * 16;
  const char* hq2 = (const char*)sm.h + (64 * w + 4 * q) * 2;
  const char* twp = (const char*)sm.tw + (64 * w + 4 * q) * 4;
  const char* tbp = (const char*)sm.tb + (64 * w + 4 * q) * 4;
  const char* bnp = (const char*)sm.bnh + (64 * w + 4 * q) * 4;

  for (int e = tid; e < LSEQ; e += NTHR) sm.xv[e] = x[(size_t)b * LSEQ + e];
#pragma unroll
  for (int g = 0; g < 3; ++g) {
    sm.tw[g][tid] = Wih0[256 * g + tid];
    sm.tb[g][tid] = bih0[256 * g + tid] + (g < 2 ? bhh0[256 * g + tid] : 0.f);
  }
  sm.bnh[tid] = bhh0[512 + tid];      // bhh_n: sits INSIDE r-multiply
  ((u32*)sm.h)[tid] = 0;              // zero buf0 hi+lo (1024 B)
  LOADA(Whh0);
  __syncthreads();

  __half* ysp = ys + (size_t)b * LSEQ * HDIM + 64 * w + 4 * q;
  int pb = 0;
#pragma unroll 1
  for (int t = 0; t < LSEQ; ++t) {
    const float xt = sm.xv[t];
    MAT_STEP(pb)
    ACFENCE
    const char* rhp = hq2 + pb * 1024;
    char* whp = (char*)hq2 + (pb ^ 1) * 1024;
#pragma unroll
    for (int S = 0; S < 4; ++S) {
      const f32x4 w4r = *(const f32x4*)(twp + S * 64);
      const f32x4 w4z = *(const f32x4*)(twp + 1024 + S * 64);
      const f32x4 w4n = *(const f32x4*)(twp + 2048 + S * 64);
      const f32x4 b4r = *(const f32x4*)(tbp + S * 64);
      const f32x4 b4z = *(const f32x4*)(tbp + 1024 + S * 64);
      const f32x4 b4n = *(const f32x4*)(tbp + 2048 + S * 64);
      const f32x4 bn4 = *(const f32x4*)(bnp + S * 64);
      const f16x4 hh = *(const f16x4*)(rhp + S * 32);
      const f16x4 hl = *(const f16x4*)(rhp + 512 + S * 32);
      f16x4 vh, vl;
#pragma unroll
      for (int r = 0; r < 4; ++r) {
        const float rr = sigm(fmaf(xt, w4r[r], b4r[r]) + ac[S][r]);
        const float zz = sigm(fmaf(xt, w4z[r], b4z[r]) + ac[4 + S][r]);
        const float nn = tanh_(fmaf(rr, ac[8 + S][r] + bn4[r],
                                    fmaf(xt, w4n[r], b4n[r])));
        const float ho = (float)hh[r] + (float)hl[r];
        const float hv = fmaf(zz, ho - nn, nn);
        vh[r] = (_Float16)hv;
        vl[r] = (_Float16)(hv - (float)vh[r]);
      }
      if (n == 0) {
        *(f16x4*)(whp + S * 32) = vh;
        *(f16x4*)(whp + 512 + S * 32) = vl;
        *(f16x4*)(ysp + 16 * S) = vh;
      }
    }
    ysp += HDIM;
    pb ^= 1;
    BAR;
  }
}

// ===== Kernel 2: GI1 = ys0 @ W_ih1^T + (bih1 + bhh1_{r,z}) — MFMA GEMM ======
__global__ __launch_bounds__(256) void gemm_gi(
    const float* __restrict__ Wih1, const float* __restrict__ bih1,
    const float* __restrict__ bhh1, const __half* __restrict__ ys,
    __half* __restrict__ gi) {
  const int lane = threadIdx.x & 63;
  const int wv = threadIdx.x >> 6;
  const size_t bt0 = (size_t)blockIdx.x << 4;
  const int n = lane & 15, q = lane >> 4;

  f16x8 bfr[8];
  const __half* yrow = ys + (bt0 + n) * HDIM + q * 8;
#pragma unroll
  for (int kk = 0; kk < 8; ++kk) bfr[kk] = *(const f16x8*)(yrow + kk * 32);

#pragma unroll 1
  for (int mt = 0; mt < 12; ++mt) {
    const int j0 = (wv * 12 + mt) << 4;
    const float* arow = Wih1 + (size_t)(j0 + n) * HDIM + q * 8;
    f32x4 acc = {0.f, 0.f, 0.f, 0.f};
#pragma unroll
    for (int kk = 0; kk < 8; ++kk) {
      const float4 a0 = *(const float4*)(arow + kk * 32);
      const float4 a1 = *(const float4*)(arow + kk * 32 + 4);
      f16x8 af;
      af[0] = (_Float16)a0.x; af[1] = (_Float16)a0.y;
      af[2] = (_Float16)a0.z; af[3] = (_Float16)a0.w;
      af[4] = (_Float16)a1.x; af[5] = (_Float16)a1.y;
      af[6] = (_Float16)a1.z; af[7] = (_Float16)a1.w;
      acc = __builtin_amdgcn_mfma_f32_16x16x32_f16(af, bfr[kk], acc, 0, 0, 0);
    }
    const int jr = j0 + (q << 2);
    __half o4[4];
#pragma unroll
    for (int r2 = 0; r2 < 4; ++r2) {
      const float bb = bih1[jr + r2] + (j0 < 512 ? bhh1[jr + r2] : 0.f);
      o4[r2] = __float2half(acc[r2] + bb);
    }
    *(uint2*)(gi + (bt0 + n) * 768 + jr) = *(uint2*)o4;
  }
}

// ====== Kernel 3: encoder GRU layer 1 (gi-driven) + autoregressive decoder ===
__global__ __launch_bounds__(NTHR, 1) void gru_l1dec(
    const float* __restrict__ Whh1, const float* __restrict__ bhh1,
    const float* __restrict__ Wdih, const float* __restrict__ Wdhh,
    const float* __restrict__ bdih, const float* __restrict__ bdhh,
    const float* __restrict__ Wo, const float* __restrict__ bo,
    const __half* __restrict__ gi, float* __restrict__ outp) {
  __shared__ Smem sm;
  const int tid = threadIdx.x;
  const int w = tid >> 6, lane = tid & 63, n = lane & 15, q = lane >> 4;
  const int b = blockIdx.x;
  DECL_MM
  char* a11p = (char*)sm.A11 + w * 10240 + n * 80 + q * 16;
  const char* hq = (const char*)sm.h + q * 16;
  const char* hq2 = (const char*)sm.h + (64 * w + 4 * q) * 2;
  const char* twp = (const char*)sm.tw + (64 * w + 4 * q) * 4;
  const char* tbp = (const char*)sm.tb + (64 * w + 4 * q) * 4;
  const char* bnp = (const char*)sm.bnh + (64 * w + 4 * q) * 4;
  const char* wop = (const char*)sm.wo + (64 * w + 4 * q) * 4;
  const char* gb0 = (const char*)sm.gib + (64 * w + 4 * q) * 2;
  const bool l24 = (lane < 24);
  const char* gsrc = (const char*)gi + (size_t)b * LSEQ * 1536 + w * 384 + lane * 16;
  char* gw0 = (char*)sm.gib + w * 384 + lane * 16;

  sm.bnh[tid] = bhh1[512 + tid];
  ((u32*)sm.h)[tid] = 0;
  LOADA(Whh1);
  if (l24) {  // stage gi[t=0] into gib[0]
    const uint4 g0 = *(const uint4*)(gsrc);
    *(uint4*)(gw0) = g0;
  }
  gsrc += 1536;
  __syncthreads();

  // ---------------- Phase 3: encoder GRU layer 1 ----------------
  int pb = 0, cur = 0;
#pragma unroll 1
  for (int t = 0; t < LSEQ; ++t) {
    uint4 gv;
    const bool pf = l24 && (t + 1 < LSEQ);
    if (pf) gv = *(const uint4*)(gsrc);  // HBM load hides under this step
    MAT_STEP(pb)
    ACFENCE
    const char* rhp = hq2 + pb * 1024;
    char* whp = (char*)hq2 + (pb ^ 1) * 1024;
    const char* gbp = gb0 + cur * 1600;
#pragma unroll
    for (int S = 0; S < 4; ++S) {
      const f16x4 g4r = *(const f16x4*)(gbp + S * 32);
      const f16x4 g4z = *(const f16x4*)(gbp + 512 + S * 32);
      const f16x4 g4n = *(const f16x4*)(gbp + 1024 + S * 32);
      const f32x4 bn4 = *(const f32x4*)(bnp + S * 64);
      const f16x4 hh = *(const f16x4*)(rhp + S * 32);
      const f16x4 hl = *(const f16x4*)(rhp + 512 + S * 32);
      f16x4 vh, vl;
#pragma unroll
      for (int r = 0; r < 4; ++r) {
        const float rr = sigm((float)g4r[r] + ac[S][r]);
        const float zz = sigm((float)g4z[r] + ac[4 + S][r]);
        const float nn = tanh_(fmaf(rr, ac[8 + S][r] + bn4[r], (float)g4n[r]));
        const float ho = (float)hh[r] + (float)hl[r];
        const float hv = fmaf(zz, ho - nn, nn);
        vh[r] = (_Float16)hv;
        vl[r] = (_Float16)(hv - (float)vh[r]);
      }
      if (n == 0) {
        *(f16x4*)(whp + S * 32) = vh;
        *(f16x4*)(whp + 512 + S * 32) = vl;
      }
    }
    if (pf) *(uint4*)(gw0 + (cur ^ 1) * 1600) = gv;  // vmcnt wait auto-inserted
    gsrc += 1536;
    pb ^= 1;
    cur ^= 1;
    BAR;
  }

  // ---------------- Phase 4: autoregressive decoder (96 steps) --------------
  LOADA(Wdhh);
#pragma unroll
  for (int g = 0; g < 3; ++g) {
    sm.tw[g][tid] = Wdih[256 * g + tid];
    sm.tb[g][tid] = bdih[256 * g + tid] + (g < 2 ? bdhh[256 * g + tid] : 0.f);
  }
  sm.bnh[tid] = bdhh[512 + tid];
  sm.wo[tid] = Wo[tid];
  if (tid == 0) sm.inp = 0.f;
  const float bov = bo[0];
  __syncthreads();

#pragma unroll 1
  for (int t = 0; t < PRED; ++t) {
    const float it = sm.inp;
    MAT_STEP(pb)
    ACFENCE
    const char* rhp = hq2 + pb * 1024;
    char* whp = (char*)hq2 + (pb ^ 1) * 1024;
    float c = 0.f;
#pragma unroll
    for (int S = 0; S < 4; ++S) {
      const f32x4 w4r = *(const f32x4*)(twp + S * 64);
      const f32x4 w4z = *(const f32x4*)(twp + 1024 + S * 64);
      const f32x4 w4n = *(const f32x4*)(twp + 2048 + S * 64);
      const f32x4 b4r = *(const f32x4*)(tbp + S * 64);
      const f32x4 b4z = *(const f32x4*)(tbp + 1024 + S * 64);
      const f32x4 b4n = *(const f32x4*)(tbp + 2048 + S * 64);
      const f32x4 bn4 = *(const f32x4*)(bnp + S * 64);
      const f32x4 wo4 = *(const f32x4*)(wop + S * 64);
      const f16x4 hh = *(const f16x4*)(rhp + S * 32);
      const f16x4 hl = *(const f16x4*)(rhp + 512 + S * 32);
      f16x4 vh, vl;
#pragma unroll
      for (int r = 0; r < 4; ++r) {
        const float rr = sigm(fmaf(it, w4r[r], b4r[r]) + ac[S][r]);
        const float zz = sigm(fmaf(it, w4z[r], b4z[r]) + ac[4 + S][r]);
        const float nn = tanh_(fmaf(rr, ac[8 + S][r] + bn4[r],
                                    fmaf(it, w4n[r], b4n[r])));
        const float ho = (float)hh[r] + (float)hl[r];
        const float hv = fmaf(zz, ho - nn, nn);
        c = fmaf(wo4[r], hv, c);
        vh[r] = (_Float16)hv;
        vl[r] = (_Float16)(hv - (float)vh[r]);
      }
      if (n == 0) {
        *(f16x4*)(whp + S * 32) = vh;
        *(f16x4*)(whp + 512 + S * 32) = vl;
      }
    }
    c += __shfl_xor(c, 16);  // sum over q-groups (rows 64w..64w+63)
    c += __shfl_xor(c, 32);
    if (lane == 0) sm.red[w] = c;
    pb ^= 1;
    BAR;
    if (tid == 0) {
      const float ov = bov + sm.red[0] + sm.red[1] + sm.red[2] + sm.red[3];
      outp[(size_t)b * PRED + t] = ov;
      sm.inp = ov;
    }
    BAR;
  }
}

extern "C" void kernel_launch(void* const* d_in, const int* in_sizes, int n_in,
                              void* d_out, int out_size, void* d_ws, size_t ws_size,
                              hipStream_t stream) {
  const float* x    = (const float*)d_in[0];
  const float* Wih0 = (const float*)d_in[1];
  const float* Whh0 = (const float*)d_in[2];
  const float* bih0 = (const float*)d_in[3];
  const float* bhh0 = (const float*)d_in[4];
  const float* Wih1 = (const float*)d_in[5];
  const float* Whh1 = (const float*)d_in[6];
  const float* bih1 = (const float*)d_in[7];
  const float* bhh1 = (const float*)d_in[8];
  const float* Wdih = (const float*)d_in[9];
  const float* Wdhh = (const float*)d_in[10];
  const float* bdih = (const float*)d_in[11];
  const float* bdhh = (const float*)d_in[12];
  const float* Wo   = (const float*)d_in[13];
  const float* bo   = (const float*)d_in[14];

  // ws layout: ys0 (f16, 64 MiB) | GI1 (f16, 192 MiB)
  __half* ys = (__half*)d_ws;
  __half* gi = ys + (size_t)256 * 512 * 256;

  gru_l0<<<256, NTHR, 0, stream>>>(x, Wih0, Whh0, bih0, bhh0, ys);
  gemm_gi<<<(256 * 512) / 16, 256, 0, stream>>>(Wih1, bih1, bhh1, ys, gi);
  gru_l1dec<<<256, NTHR, 0, stream>>>(Whh1, bhh1, Wdih, Wdhh, bdih, bdhh,
                                      Wo, bo, gi, (float*)d_out);
}

// Round 5
// 2650.890 us; speedup vs baseline: 7.6932x; 1.8766x over previous
//
#include <hip/hip_runtime.h>
#include <hip/hip_fp16.h>

#define HDIM 256
#define LSEQ 512
#define PRED 96
#define NTHR 256  // 4 waves; wave w owns h-rows [64w, 64w+64)

typedef _Float16 f16x8 __attribute__((ext_vector_type(8)));
typedef _Float16 f16x4 __attribute__((ext_vector_type(4)));
typedef float f32x4 __attribute__((ext_vector_type(4)));
typedef unsigned int u32;

__device__ __forceinline__ float sigm(float x) { return 1.f / (1.f + __expf(-x)); }
__device__ __forceinline__ float tanh_(float x) { float t = __expf(2.f * x); return 1.f - 2.f / (t + 1.f); }
// lane ^= 1 exchange, pure VALU DPP (quad_perm [1,0,3,2]) — proven R0 pattern
__device__ __forceinline__ float dppx1(float v) {
  return __builtin_bit_cast(float, __builtin_amdgcn_update_dpp(
      0, __builtin_bit_cast(int, v), 0xB1, 0xF, 0xF, true));
}

// One batch column per block, 256 blocks. 4 waves = 1 wave/SIMD (512-reg
// budget: the only shape fitting W_hh-f16 = 1536 regs/block, R2/R4 lesson).
// Pair-trick: B col n carries h_hi (n even) / h_lo (n odd) -> ONE MFMA pass
// computes both; DPP xor1 pair-sum recombines. 96 MFMA/wave/step (was 192).
struct __align__(16) Smem {
  _Float16 h[2][2][256];   // [buf][hi/lo][row]: h split f16 hi+lo == f32
  _Float16 A11[4][5120];   // per-wave LDS A-tile [kt][row n][40] (pad 32->40)
  float tw[3][256], tb[3][256], bnh[256], wo[256];
  float xv[LSEQ];
  float red[2][4];         // decoder partial sums, double-buffered
};  // ~54 KB

#define CAST_A(DST, SRC) asm("" : "=a"(DST) : "0"(SRC))

#define DECL_MM                                                                \
  f16x8 Aa[6][8]; /* 192 AGPR */                                               \
  f16x8 Av[5][8]; /* 160 VGPR */                                               \
  f32x4 ac[12];   /* 48 AGPR accumulators */                                   \
  f32x4 zc;       /* zero C-operand, AGPR */                                   \
  { f32x4 z4 = {0.f, 0.f, 0.f, 0.f}; asm("" : "=a"(zc) : "0"(z4)); }

// A-frag load (m89/m91 layout, proven R1/R2/R4): lane(n,q) holds rows mb+n,
// k = 32kt + 8q + i. fp32 -> f16 RN. tau 0-5 AGPR, 6-10 VGPR, 11 LDS.
#define LOADA(WPTR)                                                            \
  _Pragma("unroll") for (int tt = 0; tt < 12; ++tt) {                          \
    _Pragma("unroll") for (int kt = 0; kt < 8; ++kt) {                         \
      const float* ap = (WPTR) +                                               \
          (size_t)(256 * (tt >> 2) + 64 * w + 16 * (tt & 3) + n) * HDIM +      \
          32 * kt + 8 * q;                                                     \
      const float4 a0 = *(const float4*)ap;                                    \
      const float4 a1 = *(const float4*)(ap + 4);                              \
      f16x8 tf;                                                                \
      tf[0] = (_Float16)a0.x; tf[1] = (_Float16)a0.y;                          \
      tf[2] = (_Float16)a0.z; tf[3] = (_Float16)a0.w;                          \
      tf[4] = (_Float16)a1.x; tf[5] = (_Float16)a1.y;                          \
      tf[6] = (_Float16)a1.z; tf[7] = (_Float16)a1.w;                          \
      if (tt < 6) { CAST_A(Aa[tt][kt], tf); }                                  \
      else if (tt < 11) { Av[tt - 6][kt] = tf; }                               \
      else { *(f16x8*)(a11p + kt * 1280) = tf; }                               \
    }                                                                          \
  }

#define MM_A_S(I, AF, B) asm("v_mfma_f32_16x16x32_f16 %0, %1, %2, %3" : "=a"(ac[I]) : "a"(AF), "v"(B), "a"(zc));
#define MM_A(I, AF, B)   asm("v_mfma_f32_16x16x32_f16 %0, %1, %2, %0" : "+a"(ac[I]) : "a"(AF), "v"(B));
#define MM_V_S(I, AF, B) asm("v_mfma_f32_16x16x32_f16 %0, %1, %2, %3" : "=a"(ac[I]) : "v"(AF), "v"(B), "a"(zc));
#define MM_V(I, AF, B)   asm("v_mfma_f32_16x16x32_f16 %0, %1, %2, %0" : "+a"(ac[I]) : "v"(AF), "v"(B));

#define R12S(KT, B, AL)                                                        \
  MM_A_S(0, Aa[0][KT], B) MM_A_S(1, Aa[1][KT], B) MM_A_S(2, Aa[2][KT], B)      \
  MM_A_S(3, Aa[3][KT], B) MM_A_S(4, Aa[4][KT], B) MM_A_S(5, Aa[5][KT], B)      \
  MM_V_S(6, Av[0][KT], B) MM_V_S(7, Av[1][KT], B) MM_V_S(8, Av[2][KT], B)      \
  MM_V_S(9, Av[3][KT], B) MM_V_S(10, Av[4][KT], B) MM_V_S(11, AL, B)
#define R12(KT, B, AL)                                                         \
  MM_A(0, Aa[0][KT], B) MM_A(1, Aa[1][KT], B) MM_A(2, Aa[2][KT], B)            \
  MM_A(3, Aa[3][KT], B) MM_A(4, Aa[4][KT], B) MM_A(5, Aa[5][KT], B)            \
  MM_V(6, Av[0][KT], B) MM_V(7, Av[1][KT], B) MM_V(8, Av[2][KT], B)            \
  MM_V(9, Av[3][KT], B) MM_V(10, Av[4][KT], B) MM_V(11, AL, B)

// D[768, hi|lo] = Whh * h. B col parity selects hi/lo (lane n&1). 96 MFMA.
// All 8 B-frags + 4-deep A11 rotation issued ahead: load-use >= 48 MFMA.
#define MAT_STEP(PB)                                                           \
  {                                                                            \
    const char* hp = hq + (PB) * 1024;                                         \
    f16x8 b0 = *(const f16x8*)(hp);                                            \
    f16x8 b1 = *(const f16x8*)(hp + 64);                                       \
    f16x8 b2 = *(const f16x8*)(hp + 128);                                      \
    f16x8 b3 = *(const f16x8*)(hp + 192);                                      \
    f16x8 a0 = *(const f16x8*)(a11p);                                          \
    f16x8 a1 = *(const f16x8*)(a11p + 1280);                                   \
    f16x8 a2 = *(const f16x8*)(a11p + 2560);                                   \
    f16x8 a3 = *(const f16x8*)(a11p + 3840);                                   \
    R12S(0, b0, a0)                                                            \
    b0 = *(const f16x8*)(hp + 256); a0 = *(const f16x8*)(a11p + 5120);         \
    R12(1, b1, a1)                                                             \
    b1 = *(const f16x8*)(hp + 320); a1 = *(const f16x8*)(a11p + 6400);         \
    R12(2, b2, a2)                                                             \
    b2 = *(const f16x8*)(hp + 384); a2 = *(const f16x8*)(a11p + 7680);         \
    R12(3, b3, a3)                                                             \
    b3 = *(const f16x8*)(hp + 448); a3 = *(const f16x8*)(a11p + 8960);         \
    R12(4, b0, a0)                                                             \
    R12(5, b1, a1)                                                             \
    R12(6, b2, a2)                                                             \
    R12(7, b3, a3)                                                             \
  }

// MFMA -> VALU(accvgpr_read) hazard fence (R4-proven)
#define ACFENCE                                                                \
  asm volatile("s_nop 7\n\ts_nop 7"                                            \
               : "+a"(ac[0]), "+a"(ac[1]), "+a"(ac[2]), "+a"(ac[3]),           \
                 "+a"(ac[4]), "+a"(ac[5]), "+a"(ac[6]), "+a"(ac[7]),           \
                 "+a"(ac[8]), "+a"(ac[9]), "+a"(ac[10]), "+a"(ac[11]));

// lgkm-only barrier: LDS handoff ordered; global stores stay in flight.
#define BAR asm volatile("s_waitcnt lgkmcnt(0)\n\ts_barrier" ::: "memory")

// Gate de-dup: lane pair (2s, 2s+1) gates sub-tile S=s only (4 rows). Select
// ac[4g+sg] via uniform cndmask tree (no runtime reg-array index, rule #20),
// then DPP xor1 pair-sum recombines hi(even lane) + lo(odd lane) partials.
#define SELG(P, G)                                                             \
  f32x4 P;                                                                     \
  { const f32x4 e0 = ac[4 * (G)], e1 = ac[4 * (G) + 1];                        \
    const f32x4 e2 = ac[4 * (G) + 2], e3 = ac[4 * (G) + 3];                    \
    const f32x4 t0 = s1 ? e1 : e0;                                             \
    const f32x4 t1 = s1 ? e3 : e2;                                             \
    P = s2 ? t1 : t0; }
#define PSUM(P)                                                                \
  { P[0] += dppx1(P[0]); P[1] += dppx1(P[1]);                                  \
    P[2] += dppx1(P[2]); P[3] += dppx1(P[3]); }

// Gate math for this lane's 4 rows; only st lanes store h (and extras).
#define GATES(GR, GZ, GN, RHOOK, STEXTRA)                                      \
  {                                                                            \
    const char* rh = hrow + pb * 1024;                                         \
    char* wh = hrow + (pb ^ 1) * 1024;                                         \
    const f16x4 hh = *(const f16x4*)(rh);                                      \
    const f16x4 hl = *(const f16x4*)(rh + 512);                                \
    const f32x4 bn4 = *(const f32x4*)bnrow;                                    \
    f16x4 vh, vl;                                                              \
    _Pragma("unroll") for (int r = 0; r < 4; ++r) {                            \
      const float rr = sigm((GR)[r] + pr[r]);                                  \
      const float zz = sigm((GZ)[r] + pz[r]);                                  \
      const float nn = tanh_(fmaf(rr, pn[r] + bn4[r], (GN)[r]));               \
      const float ho = (float)hh[r] + (float)hl[r];                            \
      const float hv = fmaf(zz, ho - nn, nn);                                  \
      vh[r] = (_Float16)hv;                                                    \
      vl[r] = (_Float16)(hv - (float)vh[r]);                                   \
      RHOOK                                                                    \
    }                                                                          \
    if (st) {                                                                  \
      *(f16x4*)(wh) = vh;                                                      \
      *(f16x4*)(wh + 512) = vl;                                                \
      STEXTRA                                                                  \
    }                                                                          \
  }

#define LANE_GEOM                                                              \
  const int tid = threadIdx.x;                                                 \
  const int w = tid >> 6, lane = tid & 63, n = lane & 15, q = lane >> 4;       \
  const int b = blockIdx.x;                                                    \
  const int sg = (n >> 1) & 3;                                                 \
  const bool s1 = (n & 2) != 0, s2 = (n & 4) != 0;                             \
  const bool st = (n == 2 * sg); /* n in {0,2,4,6}: unique (S,q) storers */    \
  const int row = 64 * w + 16 * sg + 4 * q;                                    \
  char* a11p = (char*)sm.A11 + w * 10240 + n * 80 + q * 16;                    \
  const char* hq = (const char*)sm.h + (n & 1) * 512 + q * 16;                 \
  char* hrow = (char*)sm.h + row * 2;                                          \
  const char* bnrow = (const char*)sm.bnh + row * 4;

// =================== Kernel 1: encoder GRU layer 0 ===========================
__global__ __launch_bounds__(NTHR, 1) void gru_l0(
    const float* __restrict__ x, const float* __restrict__ Wih0,
    const float* __restrict__ Whh0, const float* __restrict__ bih0,
    const float* __restrict__ bhh0, __half* __restrict__ ys) {
  __shared__ Smem sm;
  LANE_GEOM
  DECL_MM
  const float* twrow = (const float*)sm.tw + row;
  const float* tbrow = (const float*)sm.tb + row;

  for (int e = tid; e < LSEQ; e += NTHR) sm.xv[e] = x[(size_t)b * LSEQ + e];
#pragma unroll
  for (int g = 0; g < 3; ++g) {
    sm.tw[g][tid] = Wih0[256 * g + tid];
    sm.tb[g][tid] = bih0[256 * g + tid] + (g < 2 ? bhh0[256 * g + tid] : 0.f);
  }
  sm.bnh[tid] = bhh0[512 + tid];      // bhh_n: sits INSIDE r-multiply
  ((u32*)sm.h)[tid] = 0;              // zero buf0 hi+lo (1024 B)
  LOADA(Whh0);
  __syncthreads();

  __half* ysp = ys + (size_t)b * LSEQ * HDIM + row;
  int pb = 0;
#pragma unroll 1
  for (int t = 0; t < LSEQ; ++t) {
    const float xt = sm.xv[t];
    MAT_STEP(pb)
    ACFENCE
    SELG(pr, 0) SELG(pz, 1) SELG(pn, 2)
    PSUM(pr) PSUM(pz) PSUM(pn)
    const f32x4 gr = *(const f32x4*)(twrow) * xt + *(const f32x4*)(tbrow);
    const f32x4 gz = *(const f32x4*)(twrow + 256) * xt + *(const f32x4*)(tbrow + 256);
    const f32x4 gn = *(const f32x4*)(twrow + 512) * xt + *(const f32x4*)(tbrow + 512);
    GATES(gr, gz, gn, ;, *(f16x4*)ysp = vh;)
    ysp += HDIM;
    pb ^= 1;
    BAR;
  }
}

// ===== Kernel 2: GI1 = ys0 @ W_ih1^T + (bih1 + bhh1_{r,z}) — MFMA GEMM ======
__global__ __launch_bounds__(256) void gemm_gi(
    const float* __restrict__ Wih1, const float* __restrict__ bih1,
    const float* __restrict__ bhh1, const __half* __restrict__ ys,
    __half* __restrict__ gi) {
  const int lane = threadIdx.x & 63;
  const int wv = threadIdx.x >> 6;
  const size_t bt0 = (size_t)blockIdx.x << 4;
  const int n = lane & 15, q = lane >> 4;

  f16x8 bfr[8];
  const __half* yrow = ys + (bt0 + n) * HDIM + q * 8;
#pragma unroll
  for (int kk = 0; kk < 8; ++kk) bfr[kk] = *(const f16x8*)(yrow + kk * 32);

#pragma unroll 1
  for (int mt = 0; mt < 12; ++mt) {
    const int j0 = (wv * 12 + mt) << 4;
    const float* arow = Wih1 + (size_t)(j0 + n) * HDIM + q * 8;
    f32x4 acc = {0.f, 0.f, 0.f, 0.f};
#pragma unroll
    for (int kk = 0; kk < 8; ++kk) {
      const float4 a0 = *(const float4*)(arow + kk * 32);
      const float4 a1 = *(const float4*)(arow + kk * 32 + 4);
      f16x8 af;
      af[0] = (_Float16)a0.x; af[1] = (_Float16)a0.y;
      af[2] = (_Float16)a0.z; af[3] = (_Float16)a0.w;
      af[4] = (_Float16)a1.x; af[5] = (_Float16)a1.y;
      af[6] = (_Float16)a1.z; af[7] = (_Float16)a1.w;
      acc = __builtin_amdgcn_mfma_f32_16x16x32_f16(af, bfr[kk], acc, 0, 0, 0);
    }
    const int jr = j0 + (q << 2);
    __half o4[4];
#pragma unroll
    for (int r2 = 0; r2 < 4; ++r2) {
      const float bb = bih1[jr + r2] + (j0 < 512 ? bhh1[jr + r2] : 0.f);
      o4[r2] = __float2half(acc[r2] + bb);
    }
    *(uint2*)(gi + (bt0 + n) * 768 + jr) = *(uint2*)o4;
  }
}

// ====== Kernel 3: encoder GRU layer 1 (gi-driven) + autoregressive decoder ===
// Direct per-lane gi prefetch (8B x3, rows this lane gates), 1 step ahead.
#define LOADGI(PF, T)                                                          \
  { const __half* gp = gi + ((size_t)b * LSEQ + (T)) * 768 + row;              \
    PF[0] = *(const uint2*)(gp);                                               \
    PF[1] = *(const uint2*)(gp + 256);                                         \
    PF[2] = *(const uint2*)(gp + 512); }

#define STEP3(PF)                                                              \
  {                                                                            \
    MAT_STEP(pb)                                                               \
    ACFENCE                                                                    \
    SELG(pr, 0) SELG(pz, 1) SELG(pn, 2)                                        \
    PSUM(pr) PSUM(pz) PSUM(pn)                                                 \
    const __half2* p0 = (const __half2*)&PF[0];                                \
    const __half2* p1 = (const __half2*)&PF[1];                                \
    const __half2* p2 = (const __half2*)&PF[2];                                \
    const float2 r01 = __half22float2(p0[0]), r23 = __half22float2(p0[1]);     \
    const float2 z01 = __half22float2(p1[0]), z23 = __half22float2(p1[1]);     \
    const float2 n01 = __half22float2(p2[0]), n23 = __half22float2(p2[1]);     \
    const f32x4 gr = {r01.x, r01.y, r23.x, r23.y};                             \
    const f32x4 gz = {z01.x, z01.y, z23.x, z23.y};                             \
    const f32x4 gn = {n01.x, n01.y, n23.x, n23.y};                             \
    GATES(gr, gz, gn, ;, ;)                                                    \
    pb ^= 1;                                                                   \
    BAR;                                                                       \
  }

__global__ __launch_bounds__(NTHR, 1) void gru_l1dec(
    const float* __restrict__ Whh1, const float* __restrict__ bhh1,
    const float* __restrict__ Wdih, const float* __restrict__ Wdhh,
    const float* __restrict__ bdih, const float* __restrict__ bdhh,
    const float* __restrict__ Wo, const float* __restrict__ bo,
    const __half* __restrict__ gi, float* __restrict__ outp) {
  __shared__ Smem sm;
  LANE_GEOM
  DECL_MM
  const float* twrow = (const float*)sm.tw + row;
  const float* tbrow = (const float*)sm.tb + row;
  const float* worow = (const float*)sm.wo + row;

  sm.bnh[tid] = bhh1[512 + tid];
  ((u32*)sm.h)[tid] = 0;
  LOADA(Whh1);
  __syncthreads();

  // ---------------- Phase 3: encoder GRU layer 1 ----------------
  uint2 pfA[3], pfB[3];
  LOADGI(pfA, 0);
  int pb = 0;
#pragma unroll 1
  for (int t = 0; t < LSEQ; t += 2) {
    LOADGI(pfB, t + 1);
    STEP3(pfA)
    LOADGI(pfA, (t + 2 < LSEQ) ? (t + 2) : (LSEQ - 1));  // clamp: harmless
    STEP3(pfB)
  }

  // ---------------- Phase 4: autoregressive decoder (96 steps) --------------
  LOADA(Wdhh);
#pragma unroll
  for (int g = 0; g < 3; ++g) {
    sm.tw[g][tid] = Wdih[256 * g + tid];
    sm.tb[g][tid] = bdih[256 * g + tid] + (g < 2 ? bdhh[256 * g + tid] : 0.f);
  }
  sm.bnh[tid] = bdhh[512 + tid];
  sm.wo[tid] = Wo[tid];
  const float bov = bo[0];
  // seed so it(0) = bov + sum(red[0]) == 0
  if (tid < 4) sm.red[0][tid] = (tid == 0) ? -bov : 0.f;
  __syncthreads();

  int rb = 0;
#pragma unroll 1
  for (int t = 0; t < PRED; ++t) {
    const f32x4 rd = *(const f32x4*)sm.red[rb];
    const float it = bov + rd[0] + rd[1] + rd[2] + rd[3];  // out(t-1)
    if (tid == 0 && t > 0) outp[(size_t)b * PRED + t - 1] = it;
    MAT_STEP(pb)
    ACFENCE
    SELG(pr, 0) SELG(pz, 1) SELG(pn, 2)
    PSUM(pr) PSUM(pz) PSUM(pn)
    const f32x4 gr = *(const f32x4*)(twrow) * it + *(const f32x4*)(tbrow);
    const f32x4 gz = *(const f32x4*)(twrow + 256) * it + *(const f32x4*)(tbrow + 256);
    const f32x4 gn = *(const f32x4*)(twrow + 512) * it + *(const f32x4*)(tbrow + 512);
    const f32x4 wo4 = *(const f32x4*)worow;
    float c = 0.f;
    GATES(gr, gz, gn, c = fmaf(wo4[r], hv, c);, ;)
    if (!st) c = 0.f;
    c += __shfl_xor(c, 2);   // sum over the 4 storer n-lanes {0,2,4,6}
    c += __shfl_xor(c, 4);
    c += __shfl_xor(c, 16);  // sum over q
    c += __shfl_xor(c, 32);
    if (lane == 0) sm.red[rb ^ 1][w] = c;
    pb ^= 1;
    rb ^= 1;
    BAR;
  }
  if (tid == 0) {
    const f32x4 rd = *(const f32x4*)sm.red[rb];
    outp[(size_t)b * PRED + PRED - 1] = bov + rd[0] + rd[1] + rd[2] + rd[3];
  }
}

extern "C" void kernel_launch(void* const* d_in, const int* in_sizes, int n_in,
                              void* d_out, int out_size, void* d_ws, size_t ws_size,
                              hipStream_t stream) {
  const float* x    = (const float*)d_in[0];
  const float* Wih0 = (const float*)d_in[1];
  const float* Whh0 = (const float*)d_in[2];
  const float* bih0 = (const float*)d_in[3];
  const float* bhh0 = (const float*)d_in[4];
  const float* Wih1 = (const float*)d_in[5];
  const float* Whh1 = (const float*)d_in[6];
  const float* bih1 = (const float*)d_in[7];
  const float* bhh1 = (const float*)d_in[8];
  const float* Wdih = (const float*)d_in[9];
  const float* Wdhh = (const float*)d_in[10];
  const float* bdih = (const float*)d_in[11];
  const float* bdhh = (const float*)d_in[12];
  const float* Wo   = (const float*)d_in[13];
  const float* bo   = (const float*)d_in[14];

  // ws layout: ys0 (f16, 64 MiB) | GI1 (f16, 192 MiB)
  __half* ys = (__half*)d_ws;
  __half* gi = ys + (size_t)256 * 512 * 256;

  gru_l0<<<256, NTHR, 0, stream>>>(x, Wih0, Whh0, bih0, bhh0, ys);
  gemm_gi<<<(256 * 512) / 16, 256, 0, stream>>>(Wih1, bih1, bhh1, ys, gi);
  gru_l1dec<<<256, NTHR, 0, stream>>>(Whh1, bhh1, Wdih, Wdhh, bdih, bdhh,
                                      Wo, bo, gi, (float*)d_out);
}